// Round 1
// baseline (47.052 us; speedup 1.0000x reference)
//
#include <hip/hip_runtime.h>

#define H    512
#define W    512
#define WSZ  7
#define PAD  3
#define TH   32
#define TW   64
#define PH   (TH + 2 * PAD)   // 38
#define PW   (TW + 2 * PAD)   // 70
#define XS_STRIDE 71          // odd stride -> 2-way (free) bank aliasing in hsum phase
#define HS_STRIDE 65          // odd stride -> conflict-free writes/reads of row sums

__global__ __launch_bounds__(256) void lvar_kernel(const float* __restrict__ x,
                                                   float* __restrict__ out) {
    __shared__ float xs [PH][XS_STRIDE];  // 38*71*4 = 10792 B
    __shared__ float hs [PH][HS_STRIDE];  //  9880 B  (row sums of x)
    __shared__ float hs2[PH][HS_STRIDE];  //  9880 B  (row sums of x^2)

    const int tx  = threadIdx.x;          // 0..63 (one wave per ty)
    const int ty  = threadIdx.y;          // 0..3
    const int tid = ty * 64 + tx;

    const int col0 = blockIdx.x * TW;
    const int row0 = blockIdx.y * TH;
    const long img_off = (long)blockIdx.z * (long)(H * W);
    const float* __restrict__ xim = x + img_off;
    float* __restrict__ oim = out + img_off;

    // ---- Phase 1: global -> LDS, padded tile with circular wrap ----
    for (int r = ty; r < PH; r += 4) {
        const int gr = (row0 + r - PAD) & (H - 1);
        const float* __restrict__ rowp = xim + gr * W;
        int gc = (col0 + tx - PAD) & (W - 1);
        xs[r][tx] = rowp[gc];
        if (tx < PW - 64) {
            gc = (col0 + tx + 64 - PAD) & (W - 1);
            xs[r][tx + 64] = rowp[gc];
        }
    }
    __syncthreads();

    // ---- Phase 2: horizontal 7-tap box sums (x and x^2), sliding window ----
    // task -> (row r in 0..37, 8-wide column segment c0)
    for (int task = tid; task < PH * 8; task += 256) {
        const int r  = task >> 3;
        const int c0 = (task & 7) * 8;
        float s = 0.f, s2 = 0.f;
        #pragma unroll
        for (int k = 0; k < WSZ; ++k) {
            const float v = xs[r][c0 + k];
            s  += v;
            s2 += v * v;
        }
        hs [r][c0] = s;
        hs2[r][c0] = s2;
        #pragma unroll
        for (int j = 1; j < 8; ++j) {
            const float va = xs[r][c0 + 6 + j];
            const float vs = xs[r][c0 + j - 1];
            s  += va - vs;
            s2 += va * va - vs * vs;
            hs [r][c0 + j] = s;
            hs2[r][c0 + j] = s2;
        }
    }
    __syncthreads();

    // ---- Phase 3: vertical 7-tap sums (sliding, in registers) + variance ----
    const float inv = 1.0f / 49.0f;
    const int r0 = ty * 8;                // each thread: rows r0..r0+7, column tx
    float s = 0.f, s2 = 0.f;
    #pragma unroll
    for (int k = 0; k < WSZ; ++k) {
        s  += hs [r0 + k][tx];
        s2 += hs2[r0 + k][tx];
    }
    {
        const float m = s * inv;
        oim[(row0 + r0) * W + col0 + tx] = s2 * inv - m * m;
    }
    #pragma unroll
    for (int j = 1; j < 8; ++j) {
        s  += hs [r0 + 6 + j][tx] - hs [r0 + j - 1][tx];
        s2 += hs2[r0 + 6 + j][tx] - hs2[r0 + j - 1][tx];
        const float m = s * inv;
        oim[(row0 + r0 + j) * W + col0 + tx] = s2 * inv - m * m;
    }
}

extern "C" void kernel_launch(void* const* d_in, const int* in_sizes, int n_in,
                              void* d_out, int out_size, void* d_ws, size_t ws_size,
                              hipStream_t stream) {
    const float* x = (const float*)d_in[0];
    float* out = (float*)d_out;
    const int nimg = in_sizes[0] / (H * W);   // 16*3 = 48
    dim3 grid(W / TW, H / TH, nimg);          // (8, 16, 48)
    dim3 block(64, 4);
    lvar_kernel<<<grid, block, 0, stream>>>(x, out);
}

// Round 2
// 28.027 us; speedup vs baseline: 1.6788x; 1.6788x over previous
//
#include <hip/hip_runtime.h>

#define H    512
#define W    512
#define WSZ  7
#define PAD  3
#define TH   32
#define TW   64
#define PH   (TH + 2 * PAD)   // 38
#define NSEG (TW / 8)         // 8 segments of 8 output columns
#define HS_STRIDE 65          // 65 % 32 == 1 -> every wave access is free 2-way aliasing

__global__ __launch_bounds__(256) void lvar_kernel(const float* __restrict__ x,
                                                   float* __restrict__ out) {
    __shared__ float hs [PH][HS_STRIDE];  // 9880 B  (row sums of x)
    __shared__ float hs2[PH][HS_STRIDE];  // 9880 B  (row sums of x^2)
    // total 19760 B -> 8 blocks/CU -> 32 waves/CU occupancy cap

    const int tx  = threadIdx.x;          // 0..63
    const int ty  = threadIdx.y;          // 0..3
    const int tid = ty * 64 + tx;

    const int col0 = blockIdx.x * TW;     // multiple of 64
    const int row0 = blockIdx.y * TH;
    const long img_off = (long)blockIdx.z * (long)(H * W);
    const float* __restrict__ xim = x + img_off;
    float* __restrict__ oim = out + img_off;

    // ---- Phase A: global -> register sliding h-sums -> LDS (no x staging) ----
    // task -> (padded row r in 0..37, 8-wide output-column segment seg)
    for (int task = tid; task < PH * NSEG; task += 256) {
        const int r   = task >> 3;
        const int seg = task & 7;
        const int gr  = (row0 + r - PAD) & (H - 1);
        const float* __restrict__ rowp = xim + gr * W;
        // need global cols [col0+8seg-3, col0+8seg+11); load aligned [base, base+16)
        const int cbase = col0 + seg * 8 - 4;   // multiple of 4 -> float4 aligned
        float v[16];
        #pragma unroll
        for (int i = 0; i < 4; ++i) {
            const int gc = (cbase + 4 * i) & (W - 1);  // wrap per float4 (512%4==0)
            const float4 f = *reinterpret_cast<const float4*>(rowp + gc);
            v[4 * i + 0] = f.x; v[4 * i + 1] = f.y;
            v[4 * i + 2] = f.z; v[4 * i + 3] = f.w;
        }
        float s = 0.f, s2 = 0.f;
        #pragma unroll
        for (int k = 1; k < 8; ++k) { s += v[k]; s2 += v[k] * v[k]; }
        const int c0 = seg * 8;
        hs [r][c0] = s;
        hs2[r][c0] = s2;
        #pragma unroll
        for (int j = 1; j < 8; ++j) {
            const float va = v[j + 7], vs = v[j];
            s  += va - vs;
            s2 += va * va - vs * vs;
            hs [r][c0 + j] = s;
            hs2[r][c0 + j] = s2;
        }
    }
    __syncthreads();

    // ---- Phase B: vertical 7-tap sliding sums + variance ----
    const float inv = 1.0f / 49.0f;
    const int r0 = ty * 8;                // each thread: rows r0..r0+7, column tx
    float s = 0.f, s2 = 0.f;
    #pragma unroll
    for (int k = 0; k < WSZ; ++k) {
        s  += hs [r0 + k][tx];
        s2 += hs2[r0 + k][tx];
    }
    {
        const float m = s * inv;
        oim[(row0 + r0) * W + col0 + tx] = s2 * inv - m * m;
    }
    #pragma unroll
    for (int j = 1; j < 8; ++j) {
        s  += hs [r0 + 6 + j][tx] - hs [r0 + j - 1][tx];
        s2 += hs2[r0 + 6 + j][tx] - hs2[r0 + j - 1][tx];
        const float m = s * inv;
        oim[(row0 + r0 + j) * W + col0 + tx] = s2 * inv - m * m;
    }
}

extern "C" void kernel_launch(void* const* d_in, const int* in_sizes, int n_in,
                              void* d_out, int out_size, void* d_ws, size_t ws_size,
                              hipStream_t stream) {
    const float* x = (const float*)d_in[0];
    float* out = (float*)d_out;
    const int nimg = in_sizes[0] / (H * W);   // 16*3 = 48
    dim3 grid(W / TW, H / TH, nimg);          // (8, 16, 48)
    dim3 block(64, 4);
    lvar_kernel<<<grid, block, 0, stream>>>(x, out);
}